// Round 2
// baseline (226.433 us; speedup 1.0000x reference)
//
#include <hip/hip_runtime.h>
#include <cstdint>

// ---------------- problem constants ----------------
#define H_IN   128
#define W_IN   128
#define C_IN   256
#define O_OUT  256
#define OH     126
#define OW     126

// ---------------- tiling ----------------
#define TY     16               // output tile height
#define TX     4                // output tile width
#define IR     (TY + 2)         // 18 input rows staged
#define ICOLS  (TX + 2)         // 6 input cols staged
#define NPIX   (IR * ICOLS)     // 108 staged pixels
#define CST    257              // per-pixel word stride in LDS (odd -> conflict-free)
#define INW    (NPIX * CST)     // 27756 words of input tile
#define NWAVES 8
#define OPW    32               // output channels per wave
#define CHUNK  16               // channels staged before flush
#define SST    17               // out-stage word stride (padded)
#define STAGEW (64 * SST)       // 1088 words per wave
#define LDS_WORDS (INW + NWAVES * STAGEW)   // 36460
#define LDS_BYTES (LDS_WORDS * 4)           // 145840 B  (<160 KiB)

// ---------------- prep: sort COO entries by output channel ----------------
// weight_indices is [nnz,4]; device dtype may be int32 (JAX default, x64 off)
// or int64. Detect at runtime: int32 layout has nonzero odd words (ih/ic
// occupy odd slots); int64 layout's odd words are all-zero high halves.
__global__ void prep_kernel(const int* __restrict__ wi, const float* __restrict__ wv,
                            int nnz, int* __restrict__ offs, int2* __restrict__ entries) {
    __shared__ int cnt[256];
    __shared__ int base[257];
    __shared__ int is32;
    const int tid = threadIdx.x;
    cnt[tid] = 0;
    if (tid == 0) is32 = 0;
    __syncthreads();
    int f = 0;
    for (int idx = tid * 2 + 1; idx < nnz * 4; idx += 512) f |= wi[idx];
    if (f) atomicOr(&is32, 1);
    __syncthreads();
    const int stride = is32 ? 4 : 8;
    const int step   = is32 ? 1 : 2;
    for (int e = tid; e < nnz; e += 256) {
        int o = wi[e * stride];
        atomicAdd(&cnt[o], 1);
    }
    __syncthreads();
    if (tid == 0) {
        int s = 0;
        for (int i = 0; i < 256; ++i) { base[i] = s; s += cnt[i]; }
        base[256] = s;
    }
    __syncthreads();
    offs[tid] = base[tid];
    if (tid == 0) offs[256] = base[256];
    cnt[tid] = base[tid];      // reuse as scatter cursor
    __syncthreads();
    for (int e = tid; e < nnz; e += 256) {
        int o = wi[e * stride];
        int h = wi[e * stride + 1 * step];
        int w = wi[e * stride + 2 * step];
        int c = wi[e * stride + 3 * step];
        // faithful scrambled mapping: flat k in (kh,kw,C), reinterpreted as (C,kh,kw)
        int k   = h * 768 + w * 256 + c;
        int cp  = k / 9;
        int rem = k - cp * 9;
        int i_  = rem / 3;
        int j_  = rem - i_ * 3;
        int meta = (i_ * ICOLS + j_) * CST + cp;   // LDS word delta for this tap/channel
        int pos = atomicAdd(&cnt[o], 1);
        entries[pos] = make_int2(meta, __float_as_int(wv[e]));
    }
}

// ---------------- main conv kernel ----------------
__global__ __launch_bounds__(512)
void conv_kernel(const float* __restrict__ in, float* __restrict__ out,
                 const int* __restrict__ offs, const int2* __restrict__ E) {
    extern __shared__ float lds[];
    const int tid  = threadIdx.x;
    const int w    = tid >> 6;
    const int lane = tid & 63;
    const int tx = blockIdx.x, ty = blockIdx.y, b = blockIdx.z;
    const int iy0 = ty * TY, ix0 = tx * TX;
    const float* inb = in + (size_t)b * (H_IN * W_IN * C_IN);

    // ---- stage input tile: 108 pixels x 256 ch, async global->LDS (width 4) ----
    // call i stages 64 contiguous words (quarter-pixel q of pixel p): lane-contiguous
    for (int i = w; i < NPIX * 4; i += NWAVES) {
        int p = i >> 2, q = i & 3;
        int r = p / ICOLS, c = p - r * ICOLS;
        int gy = iy0 + r, gx = ix0 + c;
        if (gy < H_IN && gx < W_IN) {          // uniform per call
            const float* src = inb + (gy * W_IN + gx) * C_IN + q * 64 + lane;
            float* dst = lds + p * CST + q * 64;   // wave-uniform LDS base
            __builtin_amdgcn_global_load_lds(
                (const __attribute__((address_space(1))) unsigned int*)(uintptr_t)src,
                (__attribute__((address_space(3))) unsigned int*)(unsigned int)(uintptr_t)dst,
                4, 0, 0);
        }
    }
    __syncthreads();   // drains vmcnt before barrier

    // ---- gather: lane = output pixel, wave owns 32 output channels ----
    const int oyl = lane >> 2, oxl = lane & 3;
    const int A = (oyl * ICOLS + oxl) * CST;   // base word of this lane's pixel
    float* stage = lds + INW + w * STAGEW;
    const int ob = w * OPW;
    int s = offs[ob];
    for (int oc = 0; oc < OPW / CHUNK; ++oc) {
        for (int oi = 0; oi < CHUNK; ++oi) {
            const int o  = ob + oc * CHUNK + oi;
            const int e2 = offs[o + 1];
            float acc0 = 0.f, acc1 = 0.f;
            int t = s;
            for (; t + 3 < e2; t += 4) {
                int2 a0 = E[t], a1 = E[t + 1], a2 = E[t + 2], a3 = E[t + 3];
                float x0 = lds[A + a0.x];
                float x1 = lds[A + a1.x];
                float x2 = lds[A + a2.x];
                float x3 = lds[A + a3.x];
                acc0 += __int_as_float(a0.y) * x0;
                acc1 += __int_as_float(a1.y) * x1;
                acc0 += __int_as_float(a2.y) * x2;
                acc1 += __int_as_float(a3.y) * x3;
            }
            for (; t < e2; ++t) {
                int2 a = E[t];
                acc0 += __int_as_float(a.y) * lds[A + a.x];
            }
            s = e2;
            stage[lane * SST + oi] = acc0 + acc1;
        }
        __syncthreads();
        // ---- flush chunk: 64 px x 16 ch, coalesced 64B segments ----
        {
            const int chp = lane >> 4;     // 0..3 : pixel sub-index
            const int chc = lane & 15;     // 0..15: channel within chunk
            const int obase = ob + oc * CHUNK;
            for (int st = 0; st < 16; ++st) {
                int p = st * 4 + chp;
                float v = stage[p * SST + chc];
                int poy = iy0 + (p >> 2), pox = ix0 + (p & 3);
                if (poy < OH && pox < OW) {
                    out[(((size_t)b * OH + poy) * OW + pox) * O_OUT + obase + chc] = v;
                }
            }
        }
        __syncthreads();
    }
}

// ---------------- host ----------------
extern "C" void kernel_launch(void* const* d_in, const int* in_sizes, int n_in,
                              void* d_out, int out_size, void* d_ws, size_t ws_size,
                              hipStream_t stream) {
    const float* input = (const float*)d_in[0];
    const int*   widx  = (const int*)d_in[1];    // int32 or int64 (runtime-detected)
    const float* wval  = (const float*)d_in[2];
    float* outp = (float*)d_out;
    const int nnz = in_sizes[2];
    const int B = in_sizes[0] / (H_IN * W_IN * C_IN);

    int*  offs    = (int*)d_ws;
    int2* entries = (int2*)((char*)d_ws + 2048);

    prep_kernel<<<1, 256, 0, stream>>>(widx, wval, nnz, offs, entries);

    static_assert(LDS_BYTES <= 160 * 1024, "LDS over budget");
    hipFuncSetAttribute((const void*)conv_kernel,
                        hipFuncAttributeMaxDynamicSharedMemorySize, LDS_BYTES);
    dim3 grid((OW + TX - 1) / TX, (OH + TY - 1) / TY, B);
    conv_kernel<<<grid, 512, LDS_BYTES, stream>>>(input, outp, offs, entries);
}

// Round 3
// 176.942 us; speedup vs baseline: 1.2797x; 1.2797x over previous
//
#include <hip/hip_runtime.h>
#include <cstdint>

// ---------------- problem constants ----------------
#define H_IN   128
#define W_IN   128
#define C_IN   256
#define O_OUT  256
#define OH     126
#define OW     126

// ---------------- tiling ----------------
#define TY     16               // output tile height
#define TX     4                // output tile width
#define IR     (TY + 2)         // 18 input rows staged
#define ICOLS  (TX + 2)         // 6 input cols staged
#define NPIX   (IR * ICOLS)     // 108 staged pixels
#define SHW    258              // halfword stride per staged pixel (256 bf16 + 2 pad)
                                //   bank(px) = px*129 mod 32 -> 2-way (free)
#define IN_HW  (NPIX * SHW)     // 27864 halfwords = 55728 B input region
#define NWAVES 8
#define OPW    32               // output channels per wave
#define SST    34               // flush-stage word stride (even -> 8B-aligned float2)
#define STG_W  (64 * SST)       // 2176 words per wave
#define LDS_BYTES (NWAVES * STG_W * 4)   // 69632 B >= 55728 (flush reuses input region)
                                         // 2 blocks/CU: 139264 <= 163840 OK

// ---------------- prep: sort COO entries by output channel ----------------
// weight_indices [nnz,4]; dtype may be int32 (JAX default) or int64 — detect:
// int32 layout has nonzero odd words (ih/ic), int64 odd words are zero highs.
__global__ void prep_kernel(const int* __restrict__ wi, const float* __restrict__ wv,
                            int nnz, int* __restrict__ offs, int2* __restrict__ entries) {
    __shared__ int cnt[256];
    __shared__ int base[257];
    __shared__ int is32;
    const int tid = threadIdx.x;
    cnt[tid] = 0;
    if (tid == 0) is32 = 0;
    __syncthreads();
    int f = 0;
    for (int idx = tid * 2 + 1; idx < nnz * 4; idx += 512) f |= wi[idx];
    if (f) atomicOr(&is32, 1);
    __syncthreads();
    const int stride = is32 ? 4 : 8;
    const int step   = is32 ? 1 : 2;
    for (int e = tid; e < nnz; e += 256) {
        int o = wi[e * stride];
        atomicAdd(&cnt[o], 1);
    }
    __syncthreads();
    if (tid == 0) {
        int s = 0;
        for (int i = 0; i < 256; ++i) { base[i] = s; s += cnt[i]; }
        base[256] = s;
    }
    __syncthreads();
    offs[tid] = base[tid];
    if (tid == 0) offs[256] = base[256];
    cnt[tid] = base[tid];      // reuse as scatter cursor
    __syncthreads();
    for (int e = tid; e < nnz; e += 256) {
        int o = wi[e * stride];
        int h = wi[e * stride + 1 * step];
        int w = wi[e * stride + 2 * step];
        int c = wi[e * stride + 3 * step];
        // faithful scrambled mapping: flat k in (kh,kw,C), reinterpreted as (C,kh,kw)
        int k   = h * 768 + w * 256 + c;
        int cp  = k / 9;
        int rem = k - cp * 9;
        int i_  = rem / 3;
        int j_  = rem - i_ * 3;
        int meta = (i_ * ICOLS + j_) * SHW + cp;   // LDS halfword delta for tap/channel
        int pos = atomicAdd(&cnt[o], 1);
        entries[pos] = make_int2(meta, __float_as_int(wv[e]));
    }
}

// round-to-nearest-even fp32 -> bf16 bits
__device__ inline unsigned short rtne_bf16(float f) {
    unsigned u = __float_as_uint(f);
    u += 0x7FFFu + ((u >> 16) & 1u);
    return (unsigned short)(u >> 16);
}

// ---------------- main conv kernel ----------------
__global__ __launch_bounds__(512, 4)
void conv_kernel(const float* __restrict__ in, float* __restrict__ out,
                 const int* __restrict__ offs, const int2* __restrict__ E) {
    extern __shared__ char smem[];
    unsigned short* ldsH = (unsigned short*)smem;
    float*          ldsF = (float*)smem;

    const int tid  = threadIdx.x;
    const int w    = tid >> 6;
    const int lane = tid & 63;
    const int tx = blockIdx.x, ty = blockIdx.y, b = blockIdx.z;
    const int iy0 = ty * TY, ix0 = tx * TX;
    const float* inb = in + (size_t)b * (H_IN * W_IN * C_IN);

    // ---- stage input tile: 108 px x 256 ch fp32 -> bf16 in LDS ----
    // wave handles whole pixel: 64 lanes x float4 (1 KB coalesced read)
    for (int p = w; p < NPIX; p += NWAVES) {
        int r = p / ICOLS, c = p - r * ICOLS;
        int gy = iy0 + r, gx = ix0 + c;
        if (gy < H_IN && gx < W_IN) {          // wave-uniform
            const float4 v = *(const float4*)(inb + ((gy * W_IN + gx) << 8) + (lane << 2));
            ushort2 lo, hi;
            lo.x = rtne_bf16(v.x); lo.y = rtne_bf16(v.y);
            hi.x = rtne_bf16(v.z); hi.y = rtne_bf16(v.w);
            unsigned short* d = ldsH + p * SHW + (lane << 2);
            *(ushort2*)(d)     = lo;           // 4B-aligned b32 writes
            *(ushort2*)(d + 2) = hi;
        }
    }
    __syncthreads();

    // ---- gather: lane = output pixel; wave owns 32 output channels ----
    const int A = ((lane >> 2) * ICOLS + (lane & 3)) * SHW;  // bank = px mod 32, 2-way free
    const int ob = w * OPW;
    float acc[OPW];
    int s = offs[ob];
#pragma unroll
    for (int oi = 0; oi < OPW; ++oi) {
        const int e2 = offs[ob + oi + 1];
        float a0 = 0.f, a1 = 0.f;
        int t = s;
        for (; t + 4 <= e2; t += 4) {
            int2 q0 = E[t], q1 = E[t + 1], q2 = E[t + 2], q3 = E[t + 3];
            float x0 = __uint_as_float(((unsigned)ldsH[A + q0.x]) << 16);
            float x1 = __uint_as_float(((unsigned)ldsH[A + q1.x]) << 16);
            float x2 = __uint_as_float(((unsigned)ldsH[A + q2.x]) << 16);
            float x3 = __uint_as_float(((unsigned)ldsH[A + q3.x]) << 16);
            a0 += __int_as_float(q0.y) * x0;
            a1 += __int_as_float(q1.y) * x1;
            a0 += __int_as_float(q2.y) * x2;
            a1 += __int_as_float(q3.y) * x3;
        }
        for (; t < e2; ++t) {
            int2 q = E[t];
            a0 += __int_as_float(q.y) * __uint_as_float(((unsigned)ldsH[A + q.x]) << 16);
        }
        acc[oi] = a0 + a1;
        s = e2;
    }

    // ---- flush: input region is dead after this barrier; reuse as transpose stage ----
    __syncthreads();
    {
        float* st = ldsF + w * STG_W + lane * SST;
#pragma unroll
        for (int k = 0; k < OPW; k += 2)
            *(float2*)(st + k) = make_float2(acc[k], acc[k + 1]);
    }
    __syncthreads();   // cross-lane transpose within wave region
    {
        const int a_  = lane >> 3;     // pixel sub-index 0..7
        const int chq = lane & 7;      // channel quad 0..7
        const float* rb = ldsF + w * STG_W;
#pragma unroll
        for (int s8 = 0; s8 < 8; ++s8) {
            int p = s8 * 8 + a_;
            float2 u0 = *(const float2*)(rb + p * SST + chq * 4);
            float2 u1 = *(const float2*)(rb + p * SST + chq * 4 + 2);
            int poy = iy0 + (p >> 2), pox = ix0 + (p & 3);
            if (poy < OH && pox < OW) {
                float4 o4 = make_float4(u0.x, u0.y, u1.x, u1.y);
                // 8 lanes per pixel -> 128 B contiguous segment
                *(float4*)(out + (((size_t)b * OH + poy) * OW + pox) * O_OUT + ob + chq * 4) = o4;
            }
        }
    }
}

// ---------------- host ----------------
extern "C" void kernel_launch(void* const* d_in, const int* in_sizes, int n_in,
                              void* d_out, int out_size, void* d_ws, size_t ws_size,
                              hipStream_t stream) {
    const float* input = (const float*)d_in[0];
    const int*   widx  = (const int*)d_in[1];    // int32 or int64 (runtime-detected)
    const float* wval  = (const float*)d_in[2];
    float* outp = (float*)d_out;
    const int nnz = in_sizes[2];
    const int B = in_sizes[0] / (H_IN * W_IN * C_IN);

    int*  offs    = (int*)d_ws;
    int2* entries = (int2*)((char*)d_ws + 2048);

    prep_kernel<<<1, 256, 0, stream>>>(widx, wval, nnz, offs, entries);

    static_assert(LDS_BYTES >= NPIX * SHW * 2, "flush stage must cover input region");
    static_assert(LDS_BYTES <= 80 * 1024, "need 2 blocks/CU");
    hipFuncSetAttribute((const void*)conv_kernel,
                        hipFuncAttributeMaxDynamicSharedMemorySize, LDS_BYTES);
    dim3 grid((OW + TX - 1) / TX, (OH + TY - 1) / TY, B);
    conv_kernel<<<grid, 512, LDS_BYTES, stream>>>(input, outp, offs, entries);
}